// Round 15
// baseline (598.612 us; speedup 1.0000x reference)
//
#include <hip/hip_runtime.h>
#include <hip/hip_bf16.h>

// SNN forward: conv1(3->64,3x3,p1) -> IF -> pool2 -> conv2(64->64) -> IF -> pool2
//              -> fc1(16384->4096) -> IF -> fc2(4096->10) -> IF -> mean over T
// T=8 N=32 IMG=64.
// conv2 and fc1 use bf16 MFMA: spikes are exactly 0/1 (exact in bf16); fp32
// weights are 3-way bf16 split (hi+mid+lo, residual <= 2^-25|w|) -> three MFMAs
// into one fp32 accumulator == fp32 dot product to within fp32 rounding noise.
// conv1 (R14): packed v_pk_fma_f32 FMA loop (-35us); x tile DMA-staged LDS.
// fc1 (R15): M-SPLIT. Block owns 128 M-rows (grid 1024 = 64nt x 8ks x 2mh) ->
// A slab halves -> LDS 40 KB -> 4 blocks/CU (was 2) -> 2x TLP against the
// barrier convoy that has capped fc1 since R5. W fetch doubles (~330 MB,
// affordable: kernel runs at ~1.1 TB/s vs 6.3 peak). Wave = 64 M x 32 outs
// (av[4], 24 MFMA/body). Accumulation order per output unchanged ->
// bit-identical output.
// conv2 (R5): A tile (zero-padded, 42.5 KB) DMA-staged per t; inner loop is
// pure ds_read_b128 + MFMA, no bounds checks; 16B-slot swizzle on DMA source.

#define T_STEPS 8
#define NB      32
#define CMID    64

typedef __bf16 bf16x2 __attribute__((ext_vector_type(2)));
typedef __bf16 bf16x4 __attribute__((ext_vector_type(4)));
typedef __bf16 bf16x8 __attribute__((ext_vector_type(8)));
typedef short  s16x4  __attribute__((ext_vector_type(4)));
typedef short  s16x8  __attribute__((ext_vector_type(8)));
typedef float  f32x2  __attribute__((ext_vector_type(2)));
typedef float  f32x4  __attribute__((ext_vector_type(4)));

struct Split3 { float h, m, l; };
__device__ __forceinline__ Split3 split3(float x) {
    Split3 s;
    __bf16 h = (__bf16)x;
    float r1 = x - (float)h;
    __bf16 m = (__bf16)r1;
    float r2 = r1 - (float)m;
    __bf16 l = (__bf16)r2;
    s.h = (float)h; s.m = (float)m; s.l = (float)l;
    return s;
}

// split 4 fp32 into three bf16x4 (hi/mid/lo), bit-identical to split3()
__device__ __forceinline__ void split3w4(float4 v, s16x4& fh, s16x4& fm,
                                         s16x4& fl) {
    float x[4] = {v.x, v.y, v.z, v.w};
    s16x4 h, m, l;
#pragma unroll
    for (int j = 0; j < 4; j++) {
        __bf16 ch = (__bf16)x[j];
        float r1 = x[j] - (float)ch;
        __bf16 cm = (__bf16)r1;
        float r2 = r1 - (float)cm;
        __bf16 cl = (__bf16)r2;
        h[j] = __builtin_bit_cast(short, ch);
        m[j] = __builtin_bit_cast(short, cm);
        l[j] = __builtin_bit_cast(short, cl);
    }
    fh = h; fm = m; fl = l;
}

// async global(16B/lane) -> LDS, wave-uniform dest base + lane*16
__device__ __forceinline__ void load_lds16(const void* g, void* l) {
    __builtin_amdgcn_global_load_lds(
        (const __attribute__((address_space(1))) void*)g,
        (__attribute__((address_space(3))) void*)l, 16, 0, 0);
}

// ------------------------------------------------- w2 -> 3-way-split frag order
__global__ void k_w2s(const float* __restrict__ w2, __bf16* __restrict__ w2s) {
    int idx = blockIdx.x * 256 + threadIdx.x;   // 36864 total
    int j    = idx & 7;
    int lane = (idx >> 3) & 63;
    int oh   = (idx >> 9) & 1;
    int kh   = (idx >> 10) & 1;
    int g    = idx >> 11;          // ch*9 + tap, 0..17
    int tap  = g % 9;
    int ch   = g / 9;
    int co = ch * 32 + oh * 16 + (lane & 15);
    int ci = kh * 32 + (lane >> 4) * 8 + j;
    float w = w2[co * 576 + ci * 9 + tap];
    Split3 s = split3(w);
    __bf16* o = w2s + (((size_t)(g * 2 + kh) * 2 + oh) * 3) * 512 + lane * 8 + j;
    o[0]    = (__bf16)s.h;
    o[512]  = (__bf16)s.m;
    o[1024] = (__bf16)s.l;
}

// ------------------------------------------ conv1 + IF + maxpool -> NHWC bf16
// x tile DMA-staged in LDS, double-buffered across t; FMA loop packed as
// v_pk_fma_f32 pairs (a0,a1)/(a2,a3). Values bit-identical to the scalar
// bounds-checked original.
__global__ __launch_bounds__(256) void k_conv1_if_pool(
        const float* __restrict__ x, const float* __restrict__ w1,
        __bf16* __restrict__ spk1p) {
    int b    = blockIdx.x;              // 1024 = 32n * 8cog * 4pht
    int n    = b >> 5;
    int cog  = (b >> 2) & 7;
    int pht  = b & 3;
    int tid  = threadIdx.x;
    int pw   = tid & 31;
    int phl  = tid >> 5;                // 0..7 (local pooled row)
    int wv   = tid >> 6;                // 0..3
    int lane = tid & 63;

    // tile row tr <-> global row gr = 16*pht - 1 + tr, tr in [0,17]
    __shared__ float Xt[2][3][18][64];  // 27.6 KB

    {   // zero both buffers once (covers never-DMA'd OOB rows for pht 0/3)
        float* xz = &Xt[0][0][0][0];
        for (int i = tid; i < 6912; i += 256) xz[i] = 0.f;
    }

    int trlo = (pht == 0) ? 1 : 0;      // valid tile rows [trlo, trhi]
    int trhi = (pht == 3) ? 16 : 17;

    // stage x[t] tile into Xt[buf]: 15 wave-uniform 4-row (1 KB) issues,
    // last issue per ci overlaps to cover the 17/18-row range exactly.
    auto stage = [&](int t, int buf) {
        const float* xb = x + (size_t)(t * NB + n) * 3 * 4096;
        for (int i = wv; i < 15; i += 4) {
            int ci  = i / 5, q = i % 5;
            int tr0 = (q < 4) ? (trlo + 4 * q) : (trhi - 3);
            int gr0 = 16 * pht - 1 + tr0;
            const float* src = xb + ci * 4096 + (gr0 + (lane >> 4)) * 64
                             + (lane & 15) * 4;
            load_lds16(src, &Xt[buf][ci][tr0][0]);
        }
    };

    __syncthreads();
    stage(0, 0);
    __syncthreads();

    bool pw0  = (pw == 0);
    bool pw31 = (pw == 31);
    int  cl   = pw0 ? 0 : (2 * pw - 1);   // clamped halo cols
    int  cr   = pw31 ? 63 : (2 * pw + 2);

    float v[8][4];
#pragma unroll
    for (int a = 0; a < 8; a++)
#pragma unroll
        for (int p = 0; p < 4; p++) v[a][p] = 0.f;

    for (int t = 0; t < T_STEPS; t++) {
        int buf = t & 1;
        if (t < T_STEPS - 1) stage(t + 1, buf ^ 1);

        float patch[3][4][4];
#pragma unroll
        for (int ci = 0; ci < 3; ci++)
#pragma unroll
            for (int dy = 0; dy < 4; dy++) {
                int tr = 2 * phl + dy;                  // 0..17
                const float* row = &Xt[buf][ci][tr][0];
                float2 mid = *(const float2*)(row + 2 * pw);
                float lv = row[cl];
                float rv = row[cr];
                patch[ci][dy][0] = pw0 ? 0.f : lv;
                patch[ci][dy][1] = mid.x;
                patch[ci][dy][2] = mid.y;
                patch[ci][dy][3] = pw31 ? 0.f : rv;
            }
        bf16x8 sv;
#pragma unroll
        for (int c8 = 0; c8 < 8; c8++) {
            int co = cog * 8 + c8;
            const float* wc = w1 + co * 27;   // wave-uniform -> s_load
            f32x2 a01 = {0.f, 0.f};           // (a0, a1): pool row ky
            f32x2 a23 = {0.f, 0.f};           // (a2, a3): pool row ky+1
#pragma unroll
            for (int ci = 0; ci < 3; ci++)
#pragma unroll
                for (int ky = 0; ky < 3; ky++)
#pragma unroll
                    for (int kx = 0; kx < 3; kx++) {
                        float w = wc[ci * 9 + ky * 3 + kx];
                        f32x2 wv2 = {w, w};
                        f32x2 p01 = {patch[ci][ky][kx],
                                     patch[ci][ky][kx + 1]};
                        f32x2 p23 = {patch[ci][ky + 1][kx],
                                     patch[ci][ky + 1][kx + 1]};
                        a01 = __builtin_elementwise_fma(wv2, p01, a01);
                        a23 = __builtin_elementwise_fma(wv2, p23, a23);
                    }
            float s0, s1, s2, s3;
            v[c8][0] += a01[0]; s0 = (v[c8][0] >= 1.f) ? 1.f : 0.f; if (s0 > 0.f) v[c8][0] = 0.f;
            v[c8][1] += a01[1]; s1 = (v[c8][1] >= 1.f) ? 1.f : 0.f; if (s1 > 0.f) v[c8][1] = 0.f;
            v[c8][2] += a23[0]; s2 = (v[c8][2] >= 1.f) ? 1.f : 0.f; if (s2 > 0.f) v[c8][2] = 0.f;
            v[c8][3] += a23[1]; s3 = (v[c8][3] >= 1.f) ? 1.f : 0.f; if (s3 > 0.f) v[c8][3] = 0.f;
            sv[c8] = (__bf16)fmaxf(fmaxf(s0, s1), fmaxf(s2, s3));
        }
        *(bf16x8*)(spk1p + ((size_t)(t * NB + n) * 1024
                            + (pht * 8 + phl) * 32 + pw) * 64 + cog * 8) = sv;

        __syncthreads();   // drains DMA (t+1 tile ready) + guards buf reuse
    }
}

// -------------------------------- conv2 (MFMA) + IF + maxpool fused, t in-kernel
__global__ __launch_bounds__(512, 2) void k_conv2_if_pool(
        const short* __restrict__ spk1p,   // [256][32][32][64] bf16 bits
        const short* __restrict__ w2s,     // [2][55296] bf16 bits (frag order)
        __bf16* __restrict__ spk2) {       // [256][64][16][16]
    int b     = blockIdx.x;                // 256 = 32n * 4s2 * 2ch
    int ch    = b & 1;
    int s2    = (b >> 1) & 3;
    int n     = b >> 3;
    int tid   = threadIdx.x;
    int lane  = tid & 63;
    int wv    = tid >> 6;                  // 0..7
    int mh    = wv >> 1, oh = wv & 1;      // mh 0..3
    int lm    = lane & 15, kq = lane >> 4;

    __shared__ short Bs[55296];            // 108 KB
    __shared__ short As[10 * 34 * 64];     // 42.5 KB

    {
        const uint4* src = (const uint4*)(w2s + (size_t)ch * 55296);
        uint4* dst = (uint4*)Bs;
        for (int i = tid; i < 6912; i += 512) dst[i] = src[i];
        uint4* za = (uint4*)As;
        for (int i = tid; i < 2720; i += 512) za[i] = (uint4){0, 0, 0, 0};
    }
    __syncthreads();
    const short* Bsw = Bs + oh * 1536;

    int wl  = lane >> 3;
    int sph = lane & 7;

    f32x4 v[4];
#pragma unroll
    for (int i = 0; i < 4; i++) v[i] = (f32x4){0.f, 0.f, 0.f, 0.f};

    int co = ch * 32 + oh * 16 + lm;
    int pH = s2 * 4 + mh;

#pragma unroll 1
    for (int t = 0; t < T_STEPS; t++) {
        const short* img = spk1p + (size_t)(t * NB + n) * 65536;

        if (t > 0) __syncthreads();
#pragma unroll
        for (int q = 0; q < 5; q++) {
            int u = q * 8 + wv;            // 0..39, wave-uniform
            int r = u >> 2;
            int quarter = u & 3;
            int hh = s2 * 8 - 1 + r;
            if ((unsigned)hh < 32u) {
                int widx = quarter * 8 + 1 + wl;
                int slog = sph ^ (widx & 7);
                const short* src = img + (size_t)(hh * 32 + widx - 1) * 64
                                       + slog * 8;
                short* dst = As + (r * 34 + quarter * 8 + 1) * 64;
                load_lds16(src, dst);
            }
        }
        __syncthreads();                   // drains DMA: As[t] ready

        f32x4 acc[4];
#pragma unroll
        for (int i = 0; i < 4; i++) acc[i] = (f32x4){0.f, 0.f, 0.f, 0.f};

#pragma unroll 1
        for (int dy = 0; dy < 3; dy++) {
#pragma unroll 1
            for (int dx = 0; dx < 3; dx++) {
                const short* bp = Bsw + (dy * 3 + dx) * 6144 + lane * 8;
                s16x8 bf[2][3];
#pragma unroll
                for (int kh = 0; kh < 2; kh++)
#pragma unroll
                    for (int sp = 0; sp < 3; sp++)
                        bf[kh][sp] = *(const s16x8*)(bp + kh * 3072 + sp * 512);
#pragma unroll
                for (int i = 0; i < 4; i++) {
                    int r    = 2 * mh + (i >> 1) + dy;              // 0..9
                    int widx = (i & 1) * 16 + lm + dx;              // 0..33
                    const short* ap = As + (r * 34 + widx) * 64;
                    s16x8 a0 = *(const s16x8*)(ap + ((kq    ) ^ (widx & 7)) * 8);
                    s16x8 a1 = *(const s16x8*)(ap + ((kq + 4) ^ (widx & 7)) * 8);
#pragma unroll
                    for (int sp = 0; sp < 3; sp++) {
                        acc[i] = __builtin_amdgcn_mfma_f32_16x16x32_bf16(
                            a0, bf[0][sp], acc[i], 0, 0, 0);
                        acc[i] = __builtin_amdgcn_mfma_f32_16x16x32_bf16(
                            a1, bf[1][sp], acc[i], 0, 0, 0);
                    }
                }
            }
        }
        float s[4][4];
#pragma unroll
        for (int i = 0; i < 4; i++)
#pragma unroll
            for (int r = 0; r < 4; r++) {
                float vv = v[i][r] + acc[i][r];
                float sp = (vv >= 1.f) ? 1.f : 0.f;
                s[i][r] = sp;
                v[i][r] = (sp > 0.f) ? 0.f : vv;
            }
        __bf16* op = spk2 + ((size_t)(t * NB + n) * 64 + co) * 256 + pH * 16
                   + kq * 2;
#pragma unroll
        for (int i2 = 0; i2 < 2; i2++) {
            float p0 = fmaxf(fmaxf(s[i2][0], s[i2][1]),
                             fmaxf(s[i2 + 2][0], s[i2 + 2][1]));
            float p1 = fmaxf(fmaxf(s[i2][2], s[i2][3]),
                             fmaxf(s[i2 + 2][2], s[i2 + 2][3]));
            bf16x2 pv = {(__bf16)p0, (__bf16)p1};
            *(bf16x2*)(op + i2 * 8) = pv;
        }
    }
}

// ----------------------------------------------------------- fc1 via bf16 MFMA
// R15: M-split. Grid 1024 = 64nt x 8ks x 2mh; block = 256 thr (4 waves:
// mq 0..1 x oh 0..1), owns 128 M-rows x 64 outs x 2048 k. LDS = A slab
// 2 x 8 KB + Wbf 2 x 12 KB = 40 KB -> 4 blocks/CU. Wave = 64 M (av[4]) x
// 32 outs -> 24 MFMA/body. Cooperative W split3 (once per K-step, pre-split
// bf16 LDS), counted-vmcnt barrier: end-of-body vmcnt(2) lgkmcnt(0) ->
// A(it+1) DMAs done + Wbf writes visible, W(it+2) reg loads in flight.
// Per-output accumulation order unchanged -> bit-identical output.
__global__ __launch_bounds__(256, 4) void k_fc1_mfma(
        const short* __restrict__ A,      // spk2 bf16 bits [256][16384]
        const float* __restrict__ W,      // fc1 [4096][16384]
        float* __restrict__ part) {       // [8][256][4096]
    int b  = blockIdx.x;                  // 1024 = 64nt * 8ks * 2mh
    int mh = b & 1;
    int ks = (b >> 1) & 7;
    int nt = b >> 4;
    int o0 = nt * 64;
    int kbase = ks * 2048;
    int mbase = mh * 128;

    int tid  = threadIdx.x;
    int lane = tid & 63;
    int wv   = tid >> 6;                  // 0..3
    int mq   = wv >> 1;                   // M quarter within the half (64 rows)
    int oh   = wv & 1;                    // output half (32 of 64)
    int lm   = lane & 15;
    int kq   = lane >> 4;

    __shared__ short Asm[2][4096];        // 2 x 8 KB A slab (swizzled)
    __shared__ short Wbf[2][6144];        // 2 x 12 KB pre-split W bf16

    // A DMA source (inverse swizzle on source; dest linear):
    // phys unit p = q*256+tid (0..511): r=p>>2 (0..127), slot=(p&3)^((r>>1)&3)
    const short* gA[2];
#pragma unroll
    for (int q = 0; q < 2; q++) {
        int p = q * 256 + tid;
        int r = p >> 2;
        int c = (p & 3) ^ ((r >> 1) & 3);
        gA[q] = A + (size_t)(mbase + r) * 16384 + kbase + c * 8;
    }

    int wrow = tid >> 2;                  // 0..63
    const float* gWf = W + (size_t)(o0 + wrow) * 16384 + kbase + (tid & 3) * 8;

    int wkc   = tid & 3;
    int wwoff = wrow * 32 + (wkc ^ ((wrow >> 1) & 3)) * 8;

    int aoff[4];                          // shorts (slab-local rows)
#pragma unroll
    for (int i = 0; i < 4; i++) {
        int r = mq * 64 + i * 16 + lm;
        aoff[i] = (r * 4 + (kq ^ ((r >> 1) & 3))) * 8;
    }
    int wroff[2];
#pragma unroll
    for (int oi = 0; oi < 2; oi++) {
        int row = (2 * oh + oi) * 16 + lm;
        wroff[oi] = row * 32 + (kq ^ ((row >> 1) & 3)) * 8;
    }

    f32x4 acc[4][2];
#pragma unroll
    for (int i = 0; i < 4; i++)
#pragma unroll
        for (int oi = 0; oi < 2; oi++) acc[i][oi] = (f32x4){0.f, 0.f, 0.f, 0.f};

    // prologue: W(0) 2xf4 load+split -> Wbf[0]; W(1) into regs; A(0) DMA
    float4 wA0 = *(const float4*)gWf;         // W it=0
    float4 wA1 = *(const float4*)(gWf + 4);
#pragma unroll
    for (int q = 0; q < 2; q++)
        load_lds16(gA[q], &Asm[0][q * 2048 + wv * 512]);
    {
        s16x4 h4, m4, l4;
        split3w4(wA0, h4, m4, l4);
        *(s16x4*)&Wbf[0][wwoff]            = h4;
        *(s16x4*)&Wbf[0][2048 + wwoff]     = m4;
        *(s16x4*)&Wbf[0][4096 + wwoff]     = l4;
        split3w4(wA1, h4, m4, l4);
        *(s16x4*)&Wbf[0][wwoff + 4]        = h4;
        *(s16x4*)&Wbf[0][2048 + wwoff + 4] = m4;
        *(s16x4*)&Wbf[0][4096 + wwoff + 4] = l4;
    }
    float4 wB0 = *(const float4*)(gWf + 32);  // W it=1
    float4 wB1 = *(const float4*)(gWf + 36);
    asm volatile("s_waitcnt vmcnt(2) lgkmcnt(0)" ::: "memory");
    __builtin_amdgcn_s_barrier();
    __builtin_amdgcn_sched_barrier(0);

    // body: ws0/ws1 hold W(it+1) fp32; wl0/wl1 receive W(it+2)
    auto body = [&](int it, float4& ws0, float4& ws1, float4& wl0,
                    float4& wl1) {
        int nb = (it + 1) & 1;
        if (it < 63) {
            // A-DMA for it+1 issued FIRST (oldest in vm queue)
#pragma unroll
            for (int q = 0; q < 2; q++)
                load_lds16(gA[q] + (it + 1) * 32,
                           &Asm[nb][q * 2048 + wv * 512]);
            __builtin_amdgcn_sched_barrier(0);   // pin: DMAs before wload
            s16x4 h4, m4, l4;
            split3w4(ws0, h4, m4, l4);
            *(s16x4*)&Wbf[nb][wwoff]            = h4;
            *(s16x4*)&Wbf[nb][2048 + wwoff]     = m4;
            *(s16x4*)&Wbf[nb][4096 + wwoff]     = l4;
            split3w4(ws1, h4, m4, l4);
            *(s16x4*)&Wbf[nb][wwoff + 4]        = h4;
            *(s16x4*)&Wbf[nb][2048 + wwoff + 4] = m4;
            *(s16x4*)&Wbf[nb][4096 + wwoff + 4] = l4;
        }
        if (it < 62) {
            wl0 = *(const float4*)(gWf + (it + 2) * 32);
            wl1 = *(const float4*)(gWf + (it + 2) * 32 + 4);
            __builtin_amdgcn_sched_barrier(0);   // pin: wload issued here
        }

        const short* as = Asm[it & 1];
        const short* wb = Wbf[it & 1];
        s16x8 av[4];
#pragma unroll
        for (int i = 0; i < 4; i++)
            av[i] = *(const s16x8*)(as + aoff[i]);
        s16x8 bfr[3][2];                  // [sp][oi]
#pragma unroll
        for (int oi = 0; oi < 2; oi++)
#pragma unroll
            for (int sp = 0; sp < 3; sp++)
                bfr[sp][oi] = *(const s16x8*)(wb + sp * 2048 + wroff[oi]);

#pragma unroll
        for (int i = 0; i < 4; i++)
#pragma unroll
            for (int oi = 0; oi < 2; oi++) {
                acc[i][oi] = __builtin_amdgcn_mfma_f32_16x16x32_bf16(
                    av[i], bfr[0][oi], acc[i][oi], 0, 0, 0);
                acc[i][oi] = __builtin_amdgcn_mfma_f32_16x16x32_bf16(
                    av[i], bfr[1][oi], acc[i][oi], 0, 0, 0);
                acc[i][oi] = __builtin_amdgcn_mfma_f32_16x16x32_bf16(
                    av[i], bfr[2][oi], acc[i][oi], 0, 0, 0);
            }

        // counted sync: A(it+1) DMAs done + ds_writes visible; W(it+2)
        // register loads stay in flight across the barrier.
        if (it < 62) {
            asm volatile("s_waitcnt vmcnt(2) lgkmcnt(0)" ::: "memory");
            __builtin_amdgcn_s_barrier();
            __builtin_amdgcn_sched_barrier(0);
        } else if (it == 62) {
            asm volatile("s_waitcnt vmcnt(0) lgkmcnt(0)" ::: "memory");
            __builtin_amdgcn_s_barrier();
            __builtin_amdgcn_sched_barrier(0);
        }
    };

#pragma unroll 1
    for (int j = 0; j < 32; ++j) {
        body(2 * j,     wB0, wB1, wA0, wA1);
        body(2 * j + 1, wA0, wA1, wB0, wB1);
    }

    int col = lane & 15;
    int rq  = (lane >> 4) * 4;
#pragma unroll
    for (int i = 0; i < 4; i++)
#pragma unroll
        for (int oi = 0; oi < 2; oi++)
#pragma unroll
            for (int r = 0; r < 4; r++) {
                int m = mbase + mq * 64 + i * 16 + rq + r;
                int o = o0 + (2 * oh + oi) * 16 + col;
                part[((size_t)ks * 256 + m) * 4096 + o] = acc[i][oi][r];
            }
}

// ----------------------------------------------- K-split reduce + IF for fc1
__global__ void k_fc1_if(const float* __restrict__ part,
                         float* __restrict__ spk3) {
    int idx = blockIdx.x * 256 + threadIdx.x;   // 131072
    int o = idx & 4095;
    int n = idx >> 12;
    float v = 0.f;
    for (int t = 0; t < T_STEPS; t++) {
        int m = t * NB + n;
        float s = 0.f;
#pragma unroll
        for (int ks = 0; ks < 8; ks++)
            s += part[((size_t)ks * 256 + m) * 4096 + o];
        v += s;
        float sp = (v >= 1.f) ? 1.f : 0.f;
        if (sp > 0.f) v = 0.f;
        spk3[(size_t)m * 4096 + o] = sp;
    }
}

// ------------------------------------------------------ fc2 + IF + time-mean
__global__ __launch_bounds__(256) void k_fc2_if_mean(
        const float* __restrict__ spk3, const float* __restrict__ fc2,
        float* __restrict__ out) {
    int b = blockIdx.x;                  // 320 = 32n * 10o
    int n = b / 10, o = b % 10;
    const float* wr = fc2 + o * 4096;
    __shared__ float red[256];
    int tid = threadIdx.x;
    float v = 0.f, cnt = 0.f;
    for (int t = 0; t < T_STEPS; t++) {
        const float* row = spk3 + (size_t)(t * NB + n) * 4096;
        float p = 0.f;
        for (int i = tid; i < 4096; i += 256) p += row[i] * wr[i];
        red[tid] = p;
        __syncthreads();
        for (int s = 128; s > 0; s >>= 1) {
            if (tid < s) red[tid] += red[tid + s];
            __syncthreads();
        }
        if (tid == 0) {
            v += red[0];
            float sp = (v >= 1.f) ? 1.f : 0.f;
            cnt += sp;
            if (sp > 0.f) v = 0.f;
        }
        __syncthreads();
    }
    if (tid == 0) out[n * 10 + o] = cnt * 0.125f;
}

// ---------------------------------------------------------------------- launch
extern "C" void kernel_launch(void* const* d_in, const int* in_sizes, int n_in,
                              void* d_out, int out_size, void* d_ws, size_t ws_size,
                              hipStream_t stream) {
    const float* x   = (const float*)d_in[0];   // [8,32,3,64,64]
    const float* w1  = (const float*)d_in[1];   // [64,3,3,3]
    const float* w2  = (const float*)d_in[2];   // [64,64,3,3]
    const float* fc1 = (const float*)d_in[3];   // [4096,16384]
    const float* fc2 = (const float*)d_in[4];   // [10,4096]
    float* out = (float*)d_out;                 // [32,10]

    float* ws = (float*)d_ws;
    // workspace layout (float slots)
    const size_t off_w2s   = 0;                          // 57344 (110592 bf16)
    const size_t off_spk1p = 57344;                      // 8388608 (16.8M bf16)
    const size_t off_spk2  = off_spk1p + 8388608;        // 2097152 (4.2M bf16)
    const size_t off_part  = off_spk2 + 2097152;         // 8388608
    const size_t off_spk3  = off_part + 8388608;         // 1048576
    __bf16* w2s   = (__bf16*)(ws + off_w2s);
    __bf16* spk1p = (__bf16*)(ws + off_spk1p);
    __bf16* spk2  = (__bf16*)(ws + off_spk2);
    float*  part  = ws + off_part;
    float*  spk3  = ws + off_spk3;

    k_w2s<<<144, 256, 0, stream>>>(w2, w2s);
    k_conv1_if_pool<<<1024, 256, 0, stream>>>(x, w1, spk1p);
    k_conv2_if_pool<<<256, 512, 0, stream>>>((const short*)spk1p,
                                             (const short*)w2s, spk2);
    k_fc1_mfma<<<1024, 256, 0, stream>>>((const short*)spk2, fc1, part);
    k_fc1_if<<<512, 256, 0, stream>>>(part, spk3);
    k_fc2_if_mean<<<320, 256, 0, stream>>>(spk3, fc2, out);
}

// Round 16
// 588.529 us; speedup vs baseline: 1.0171x; 1.0171x over previous
//
#include <hip/hip_runtime.h>
#include <hip/hip_bf16.h>

// SNN forward: conv1(3->64,3x3,p1) -> IF -> pool2 -> conv2(64->64) -> IF -> pool2
//              -> fc1(16384->4096) -> IF -> fc2(4096->10) -> IF -> mean over T
// T=8 N=32 IMG=64.
// conv2 and fc1 use bf16 MFMA: spikes are exactly 0/1 (exact in bf16); fp32
// weights are 3-way bf16 split (hi+mid+lo, residual <= 2^-25|w|) -> three MFMAs
// into one fp32 accumulator == fp32 dot product to within fp32 rounding noise.
// conv1 (R14): packed v_pk_fma_f32 FMA loop; x tile DMA-staged LDS.
// fc1 (R16): reverted to R14's 256-thread/2-block-per-CU config (R15's M-split
// regressed: 2x TLP didn't cover doubled W fetch + halved MFMA/ds_read ratio).
// Added T5 s_setprio around the MFMA cluster (body has DMA/VALU/MFMA role
// diversity across 8 waves + 2 blocks/CU).
// conv2 (R5): A tile (zero-padded, 42.5 KB) DMA-staged per t; inner loop is
// pure ds_read_b128 + MFMA, no bounds checks; 16B-slot swizzle on DMA source.
// Launch order: conv1 first (doesn't need w2s), then k_w2s, then conv2.

#define T_STEPS 8
#define NB      32
#define CMID    64

typedef __bf16 bf16x2 __attribute__((ext_vector_type(2)));
typedef __bf16 bf16x4 __attribute__((ext_vector_type(4)));
typedef __bf16 bf16x8 __attribute__((ext_vector_type(8)));
typedef short  s16x4  __attribute__((ext_vector_type(4)));
typedef short  s16x8  __attribute__((ext_vector_type(8)));
typedef float  f32x2  __attribute__((ext_vector_type(2)));
typedef float  f32x4  __attribute__((ext_vector_type(4)));

struct Split3 { float h, m, l; };
__device__ __forceinline__ Split3 split3(float x) {
    Split3 s;
    __bf16 h = (__bf16)x;
    float r1 = x - (float)h;
    __bf16 m = (__bf16)r1;
    float r2 = r1 - (float)m;
    __bf16 l = (__bf16)r2;
    s.h = (float)h; s.m = (float)m; s.l = (float)l;
    return s;
}

// split 4 fp32 into three bf16x4 (hi/mid/lo), bit-identical to split3()
__device__ __forceinline__ void split3w4(float4 v, s16x4& fh, s16x4& fm,
                                         s16x4& fl) {
    float x[4] = {v.x, v.y, v.z, v.w};
    s16x4 h, m, l;
#pragma unroll
    for (int j = 0; j < 4; j++) {
        __bf16 ch = (__bf16)x[j];
        float r1 = x[j] - (float)ch;
        __bf16 cm = (__bf16)r1;
        float r2 = r1 - (float)cm;
        __bf16 cl = (__bf16)r2;
        h[j] = __builtin_bit_cast(short, ch);
        m[j] = __builtin_bit_cast(short, cm);
        l[j] = __builtin_bit_cast(short, cl);
    }
    fh = h; fm = m; fl = l;
}

// async global(16B/lane) -> LDS, wave-uniform dest base + lane*16
__device__ __forceinline__ void load_lds16(const void* g, void* l) {
    __builtin_amdgcn_global_load_lds(
        (const __attribute__((address_space(1))) void*)g,
        (__attribute__((address_space(3))) void*)l, 16, 0, 0);
}

// ------------------------------------------------- w2 -> 3-way-split frag order
__global__ void k_w2s(const float* __restrict__ w2, __bf16* __restrict__ w2s) {
    int idx = blockIdx.x * 256 + threadIdx.x;   // 36864 total
    int j    = idx & 7;
    int lane = (idx >> 3) & 63;
    int oh   = (idx >> 9) & 1;
    int kh   = (idx >> 10) & 1;
    int g    = idx >> 11;          // ch*9 + tap, 0..17
    int tap  = g % 9;
    int ch   = g / 9;
    int co = ch * 32 + oh * 16 + (lane & 15);
    int ci = kh * 32 + (lane >> 4) * 8 + j;
    float w = w2[co * 576 + ci * 9 + tap];
    Split3 s = split3(w);
    __bf16* o = w2s + (((size_t)(g * 2 + kh) * 2 + oh) * 3) * 512 + lane * 8 + j;
    o[0]    = (__bf16)s.h;
    o[512]  = (__bf16)s.m;
    o[1024] = (__bf16)s.l;
}

// ------------------------------------------ conv1 + IF + maxpool -> NHWC bf16
// x tile DMA-staged in LDS, double-buffered across t; FMA loop packed as
// v_pk_fma_f32 pairs (a0,a1)/(a2,a3). Values bit-identical to the scalar
// bounds-checked original.
__global__ __launch_bounds__(256) void k_conv1_if_pool(
        const float* __restrict__ x, const float* __restrict__ w1,
        __bf16* __restrict__ spk1p) {
    int b    = blockIdx.x;              // 1024 = 32n * 8cog * 4pht
    int n    = b >> 5;
    int cog  = (b >> 2) & 7;
    int pht  = b & 3;
    int tid  = threadIdx.x;
    int pw   = tid & 31;
    int phl  = tid >> 5;                // 0..7 (local pooled row)
    int wv   = tid >> 6;                // 0..3
    int lane = tid & 63;

    // tile row tr <-> global row gr = 16*pht - 1 + tr, tr in [0,17]
    __shared__ float Xt[2][3][18][64];  // 27.6 KB

    {   // zero both buffers once (covers never-DMA'd OOB rows for pht 0/3)
        float* xz = &Xt[0][0][0][0];
        for (int i = tid; i < 6912; i += 256) xz[i] = 0.f;
    }

    int trlo = (pht == 0) ? 1 : 0;      // valid tile rows [trlo, trhi]
    int trhi = (pht == 3) ? 16 : 17;

    // stage x[t] tile into Xt[buf]: 15 wave-uniform 4-row (1 KB) issues,
    // last issue per ci overlaps to cover the 17/18-row range exactly.
    auto stage = [&](int t, int buf) {
        const float* xb = x + (size_t)(t * NB + n) * 3 * 4096;
        for (int i = wv; i < 15; i += 4) {
            int ci  = i / 5, q = i % 5;
            int tr0 = (q < 4) ? (trlo + 4 * q) : (trhi - 3);
            int gr0 = 16 * pht - 1 + tr0;
            const float* src = xb + ci * 4096 + (gr0 + (lane >> 4)) * 64
                             + (lane & 15) * 4;
            load_lds16(src, &Xt[buf][ci][tr0][0]);
        }
    };

    __syncthreads();
    stage(0, 0);
    __syncthreads();

    bool pw0  = (pw == 0);
    bool pw31 = (pw == 31);
    int  cl   = pw0 ? 0 : (2 * pw - 1);   // clamped halo cols
    int  cr   = pw31 ? 63 : (2 * pw + 2);

    float v[8][4];
#pragma unroll
    for (int a = 0; a < 8; a++)
#pragma unroll
        for (int p = 0; p < 4; p++) v[a][p] = 0.f;

    for (int t = 0; t < T_STEPS; t++) {
        int buf = t & 1;
        if (t < T_STEPS - 1) stage(t + 1, buf ^ 1);

        float patch[3][4][4];
#pragma unroll
        for (int ci = 0; ci < 3; ci++)
#pragma unroll
            for (int dy = 0; dy < 4; dy++) {
                int tr = 2 * phl + dy;                  // 0..17
                const float* row = &Xt[buf][ci][tr][0];
                float2 mid = *(const float2*)(row + 2 * pw);
                float lv = row[cl];
                float rv = row[cr];
                patch[ci][dy][0] = pw0 ? 0.f : lv;
                patch[ci][dy][1] = mid.x;
                patch[ci][dy][2] = mid.y;
                patch[ci][dy][3] = pw31 ? 0.f : rv;
            }
        bf16x8 sv;
#pragma unroll
        for (int c8 = 0; c8 < 8; c8++) {
            int co = cog * 8 + c8;
            const float* wc = w1 + co * 27;   // wave-uniform -> s_load
            f32x2 a01 = {0.f, 0.f};           // (a0, a1): pool row ky
            f32x2 a23 = {0.f, 0.f};           // (a2, a3): pool row ky+1
#pragma unroll
            for (int ci = 0; ci < 3; ci++)
#pragma unroll
                for (int ky = 0; ky < 3; ky++)
#pragma unroll
                    for (int kx = 0; kx < 3; kx++) {
                        float w = wc[ci * 9 + ky * 3 + kx];
                        f32x2 wv2 = {w, w};
                        f32x2 p01 = {patch[ci][ky][kx],
                                     patch[ci][ky][kx + 1]};
                        f32x2 p23 = {patch[ci][ky + 1][kx],
                                     patch[ci][ky + 1][kx + 1]};
                        a01 = __builtin_elementwise_fma(wv2, p01, a01);
                        a23 = __builtin_elementwise_fma(wv2, p23, a23);
                    }
            float s0, s1, s2, s3;
            v[c8][0] += a01[0]; s0 = (v[c8][0] >= 1.f) ? 1.f : 0.f; if (s0 > 0.f) v[c8][0] = 0.f;
            v[c8][1] += a01[1]; s1 = (v[c8][1] >= 1.f) ? 1.f : 0.f; if (s1 > 0.f) v[c8][1] = 0.f;
            v[c8][2] += a23[0]; s2 = (v[c8][2] >= 1.f) ? 1.f : 0.f; if (s2 > 0.f) v[c8][2] = 0.f;
            v[c8][3] += a23[1]; s3 = (v[c8][3] >= 1.f) ? 1.f : 0.f; if (s3 > 0.f) v[c8][3] = 0.f;
            sv[c8] = (__bf16)fmaxf(fmaxf(s0, s1), fmaxf(s2, s3));
        }
        *(bf16x8*)(spk1p + ((size_t)(t * NB + n) * 1024
                            + (pht * 8 + phl) * 32 + pw) * 64 + cog * 8) = sv;

        __syncthreads();   // drains DMA (t+1 tile ready) + guards buf reuse
    }
}

// -------------------------------- conv2 (MFMA) + IF + maxpool fused, t in-kernel
__global__ __launch_bounds__(512, 2) void k_conv2_if_pool(
        const short* __restrict__ spk1p,   // [256][32][32][64] bf16 bits
        const short* __restrict__ w2s,     // [2][55296] bf16 bits (frag order)
        __bf16* __restrict__ spk2) {       // [256][64][16][16]
    int b     = blockIdx.x;                // 256 = 32n * 4s2 * 2ch
    int ch    = b & 1;
    int s2    = (b >> 1) & 3;
    int n     = b >> 3;
    int tid   = threadIdx.x;
    int lane  = tid & 63;
    int wv    = tid >> 6;                  // 0..7
    int mh    = wv >> 1, oh = wv & 1;      // mh 0..3
    int lm    = lane & 15, kq = lane >> 4;

    __shared__ short Bs[55296];            // 108 KB
    __shared__ short As[10 * 34 * 64];     // 42.5 KB

    {
        const uint4* src = (const uint4*)(w2s + (size_t)ch * 55296);
        uint4* dst = (uint4*)Bs;
        for (int i = tid; i < 6912; i += 512) dst[i] = src[i];
        uint4* za = (uint4*)As;
        for (int i = tid; i < 2720; i += 512) za[i] = (uint4){0, 0, 0, 0};
    }
    __syncthreads();
    const short* Bsw = Bs + oh * 1536;

    int wl  = lane >> 3;
    int sph = lane & 7;

    f32x4 v[4];
#pragma unroll
    for (int i = 0; i < 4; i++) v[i] = (f32x4){0.f, 0.f, 0.f, 0.f};

    int co = ch * 32 + oh * 16 + lm;
    int pH = s2 * 4 + mh;

#pragma unroll 1
    for (int t = 0; t < T_STEPS; t++) {
        const short* img = spk1p + (size_t)(t * NB + n) * 65536;

        if (t > 0) __syncthreads();
#pragma unroll
        for (int q = 0; q < 5; q++) {
            int u = q * 8 + wv;            // 0..39, wave-uniform
            int r = u >> 2;
            int quarter = u & 3;
            int hh = s2 * 8 - 1 + r;
            if ((unsigned)hh < 32u) {
                int widx = quarter * 8 + 1 + wl;
                int slog = sph ^ (widx & 7);
                const short* src = img + (size_t)(hh * 32 + widx - 1) * 64
                                       + slog * 8;
                short* dst = As + (r * 34 + quarter * 8 + 1) * 64;
                load_lds16(src, dst);
            }
        }
        __syncthreads();                   // drains DMA: As[t] ready

        f32x4 acc[4];
#pragma unroll
        for (int i = 0; i < 4; i++) acc[i] = (f32x4){0.f, 0.f, 0.f, 0.f};

#pragma unroll 1
        for (int dy = 0; dy < 3; dy++) {
#pragma unroll 1
            for (int dx = 0; dx < 3; dx++) {
                const short* bp = Bsw + (dy * 3 + dx) * 6144 + lane * 8;
                s16x8 bf[2][3];
#pragma unroll
                for (int kh = 0; kh < 2; kh++)
#pragma unroll
                    for (int sp = 0; sp < 3; sp++)
                        bf[kh][sp] = *(const s16x8*)(bp + kh * 3072 + sp * 512);
#pragma unroll
                for (int i = 0; i < 4; i++) {
                    int r    = 2 * mh + (i >> 1) + dy;              // 0..9
                    int widx = (i & 1) * 16 + lm + dx;              // 0..33
                    const short* ap = As + (r * 34 + widx) * 64;
                    s16x8 a0 = *(const s16x8*)(ap + ((kq    ) ^ (widx & 7)) * 8);
                    s16x8 a1 = *(const s16x8*)(ap + ((kq + 4) ^ (widx & 7)) * 8);
#pragma unroll
                    for (int sp = 0; sp < 3; sp++) {
                        acc[i] = __builtin_amdgcn_mfma_f32_16x16x32_bf16(
                            a0, bf[0][sp], acc[i], 0, 0, 0);
                        acc[i] = __builtin_amdgcn_mfma_f32_16x16x32_bf16(
                            a1, bf[1][sp], acc[i], 0, 0, 0);
                    }
                }
            }
        }
        float s[4][4];
#pragma unroll
        for (int i = 0; i < 4; i++)
#pragma unroll
            for (int r = 0; r < 4; r++) {
                float vv = v[i][r] + acc[i][r];
                float sp = (vv >= 1.f) ? 1.f : 0.f;
                s[i][r] = sp;
                v[i][r] = (sp > 0.f) ? 0.f : vv;
            }
        __bf16* op = spk2 + ((size_t)(t * NB + n) * 64 + co) * 256 + pH * 16
                   + kq * 2;
#pragma unroll
        for (int i2 = 0; i2 < 2; i2++) {
            float p0 = fmaxf(fmaxf(s[i2][0], s[i2][1]),
                             fmaxf(s[i2 + 2][0], s[i2 + 2][1]));
            float p1 = fmaxf(fmaxf(s[i2][2], s[i2][3]),
                             fmaxf(s[i2 + 2][2], s[i2 + 2][3]));
            bf16x2 pv = {(__bf16)p0, (__bf16)p1};
            *(bf16x2*)(op + i2 * 8) = pv;
        }
    }
}

// ----------------------------------------------------------- fc1 via bf16 MFMA
// R14 config (best measured): 256-thread blocks (4 waves: mq 0..1 x oh 0..1),
// grid 512 = 2 blocks/CU. Wave owns 128 M-rows (av[8]) x 32 outputs.
// Cooperative W split3 once per K-step -> pre-split bf16 LDS; A slab DMA
// double-buffer; counted-vmcnt barrier. + T5 setprio around MFMA cluster.
__global__ __launch_bounds__(256, 2) void k_fc1_mfma(
        const short* __restrict__ A,      // spk2 bf16 bits [256][16384]
        const float* __restrict__ W,      // fc1 [4096][16384]
        float* __restrict__ part) {       // [8][256][4096]
    int b  = blockIdx.x;                  // 512 = 64nt * 8ks
    int nt = b & 63;
    int ks = b >> 6;
    int o0 = nt * 64;
    int kbase = ks * 2048;

    int tid  = threadIdx.x;
    int lane = tid & 63;
    int wv   = tid >> 6;                  // 0..3
    int mq   = wv >> 1;                   // M half (128 rows)
    int oh   = wv & 1;                    // output half (32 of 64)
    int lm   = lane & 15;
    int kq   = lane >> 4;

    __shared__ short Asm[2][8192];        // 2 x 16 KB A slab (swizzled)
    __shared__ short Wbf[2][6144];        // 2 x 12 KB pre-split W bf16

    const short* gA[4];
#pragma unroll
    for (int q = 0; q < 4; q++) {
        int p = q * 256 + tid;
        int r = p >> 2;
        int c = (p & 3) ^ ((r >> 1) & 3);
        gA[q] = A + (size_t)r * 16384 + kbase + c * 8;
    }

    int wrow = tid >> 2;                  // 0..63
    const float* gWf = W + (size_t)(o0 + wrow) * 16384 + kbase + (tid & 3) * 8;

    int wkc   = tid & 3;
    int wwoff = wrow * 32 + (wkc ^ ((wrow >> 1) & 3)) * 8;

    int aoff[8];
#pragma unroll
    for (int i = 0; i < 8; i++) {
        int r = mq * 128 + i * 16 + lm;
        aoff[i] = (r * 4 + (kq ^ ((r >> 1) & 3))) * 8;
    }
    int wroff[2];
#pragma unroll
    for (int oi = 0; oi < 2; oi++) {
        int row = (2 * oh + oi) * 16 + lm;
        wroff[oi] = row * 32 + (kq ^ ((row >> 1) & 3)) * 8;
    }

    f32x4 acc[8][2];
#pragma unroll
    for (int i = 0; i < 8; i++)
#pragma unroll
        for (int oi = 0; oi < 2; oi++) acc[i][oi] = (f32x4){0.f, 0.f, 0.f, 0.f};

    float4 wA0 = *(const float4*)gWf;         // W it=0
    float4 wA1 = *(const float4*)(gWf + 4);
#pragma unroll
    for (int q = 0; q < 4; q++)
        load_lds16(gA[q], &Asm[0][q * 2048 + wv * 512]);
    {
        s16x4 h4, m4, l4;
        split3w4(wA0, h4, m4, l4);
        *(s16x4*)&Wbf[0][wwoff]            = h4;
        *(s16x4*)&Wbf[0][2048 + wwoff]     = m4;
        *(s16x4*)&Wbf[0][4096 + wwoff]     = l4;
        split3w4(wA1, h4, m4, l4);
        *(s16x4*)&Wbf[0][wwoff + 4]        = h4;
        *(s16x4*)&Wbf[0][2048 + wwoff + 4] = m4;
        *(s16x4*)&Wbf[0][4096 + wwoff + 4] = l4;
    }
    float4 wB0 = *(const float4*)(gWf + 32);  // W it=1
    float4 wB1 = *(const float4*)(gWf + 36);
    asm volatile("s_waitcnt vmcnt(2) lgkmcnt(0)" ::: "memory");
    __builtin_amdgcn_s_barrier();
    __builtin_amdgcn_sched_barrier(0);

    auto body = [&](int it, float4& ws0, float4& ws1, float4& wl0,
                    float4& wl1) {
        int nb = (it + 1) & 1;
        if (it < 63) {
#pragma unroll
            for (int q = 0; q < 4; q++)
                load_lds16(gA[q] + (it + 1) * 32,
                           &Asm[nb][q * 2048 + wv * 512]);
            __builtin_amdgcn_sched_barrier(0);   // pin: DMAs before wload
            s16x4 h4, m4, l4;
            split3w4(ws0, h4, m4, l4);
            *(s16x4*)&Wbf[nb][wwoff]            = h4;
            *(s16x4*)&Wbf[nb][2048 + wwoff]     = m4;
            *(s16x4*)&Wbf[nb][4096 + wwoff]     = l4;
            split3w4(ws1, h4, m4, l4);
            *(s16x4*)&Wbf[nb][wwoff + 4]        = h4;
            *(s16x4*)&Wbf[nb][2048 + wwoff + 4] = m4;
            *(s16x4*)&Wbf[nb][4096 + wwoff + 4] = l4;
        }
        if (it < 62) {
            wl0 = *(const float4*)(gWf + (it + 2) * 32);
            wl1 = *(const float4*)(gWf + (it + 2) * 32 + 4);
            __builtin_amdgcn_sched_barrier(0);   // pin: wload issued here
        }

        const short* as = Asm[it & 1];
        const short* wb = Wbf[it & 1];
        s16x8 av[8];
#pragma unroll
        for (int i = 0; i < 8; i++)
            av[i] = *(const s16x8*)(as + aoff[i]);
        s16x8 bfr[3][2];
#pragma unroll
        for (int oi = 0; oi < 2; oi++)
#pragma unroll
            for (int sp = 0; sp < 3; sp++)
                bfr[sp][oi] = *(const s16x8*)(wb + sp * 2048 + wroff[oi]);

        __builtin_amdgcn_s_setprio(1);
#pragma unroll
        for (int i = 0; i < 8; i++)
#pragma unroll
            for (int oi = 0; oi < 2; oi++) {
                acc[i][oi] = __builtin_amdgcn_mfma_f32_16x16x32_bf16(
                    av[i], bfr[0][oi], acc[i][oi], 0, 0, 0);
                acc[i][oi] = __builtin_amdgcn_mfma_f32_16x16x32_bf16(
                    av[i], bfr[1][oi], acc[i][oi], 0, 0, 0);
                acc[i][oi] = __builtin_amdgcn_mfma_f32_16x16x32_bf16(
                    av[i], bfr[2][oi], acc[i][oi], 0, 0, 0);
            }
        __builtin_amdgcn_s_setprio(0);

        if (it < 62) {
            asm volatile("s_waitcnt vmcnt(2) lgkmcnt(0)" ::: "memory");
            __builtin_amdgcn_s_barrier();
            __builtin_amdgcn_sched_barrier(0);
        } else if (it == 62) {
            asm volatile("s_waitcnt vmcnt(0) lgkmcnt(0)" ::: "memory");
            __builtin_amdgcn_s_barrier();
            __builtin_amdgcn_sched_barrier(0);
        }
    };

#pragma unroll 1
    for (int j = 0; j < 32; ++j) {
        body(2 * j,     wB0, wB1, wA0, wA1);
        body(2 * j + 1, wA0, wA1, wB0, wB1);
    }

    int col = lane & 15;
    int rq  = (lane >> 4) * 4;
#pragma unroll
    for (int i = 0; i < 8; i++)
#pragma unroll
        for (int oi = 0; oi < 2; oi++)
#pragma unroll
            for (int r = 0; r < 4; r++) {
                int m = mq * 128 + i * 16 + rq + r;
                int o = o0 + (2 * oh + oi) * 16 + col;
                part[((size_t)ks * 256 + m) * 4096 + o] = acc[i][oi][r];
            }
}

// ----------------------------------------------- K-split reduce + IF for fc1
__global__ void k_fc1_if(const float* __restrict__ part,
                         float* __restrict__ spk3) {
    int idx = blockIdx.x * 256 + threadIdx.x;   // 131072
    int o = idx & 4095;
    int n = idx >> 12;
    float v = 0.f;
    for (int t = 0; t < T_STEPS; t++) {
        int m = t * NB + n;
        float s = 0.f;
#pragma unroll
        for (int ks = 0; ks < 8; ks++)
            s += part[((size_t)ks * 256 + m) * 4096 + o];
        v += s;
        float sp = (v >= 1.f) ? 1.f : 0.f;
        if (sp > 0.f) v = 0.f;
        spk3[(size_t)m * 4096 + o] = sp;
    }
}

// ------------------------------------------------------ fc2 + IF + time-mean
__global__ __launch_bounds__(256) void k_fc2_if_mean(
        const float* __restrict__ spk3, const float* __restrict__ fc2,
        float* __restrict__ out) {
    int b = blockIdx.x;                  // 320 = 32n * 10o
    int n = b / 10, o = b % 10;
    const float* wr = fc2 + o * 4096;
    __shared__ float red[256];
    int tid = threadIdx.x;
    float v = 0.f, cnt = 0.f;
    for (int t = 0; t < T_STEPS; t++) {
        const float* row = spk3 + (size_t)(t * NB + n) * 4096;
        float p = 0.f;
        for (int i = tid; i < 4096; i += 256) p += row[i] * wr[i];
        red[tid] = p;
        __syncthreads();
        for (int s = 128; s > 0; s >>= 1) {
            if (tid < s) red[tid] += red[tid + s];
            __syncthreads();
        }
        if (tid == 0) {
            v += red[0];
            float sp = (v >= 1.f) ? 1.f : 0.f;
            cnt += sp;
            if (sp > 0.f) v = 0.f;
        }
        __syncthreads();
    }
    if (tid == 0) out[n * 10 + o] = cnt * 0.125f;
}

// ---------------------------------------------------------------------- launch
extern "C" void kernel_launch(void* const* d_in, const int* in_sizes, int n_in,
                              void* d_out, int out_size, void* d_ws, size_t ws_size,
                              hipStream_t stream) {
    const float* x   = (const float*)d_in[0];   // [8,32,3,64,64]
    const float* w1  = (const float*)d_in[1];   // [64,3,3,3]
    const float* w2  = (const float*)d_in[2];   // [64,64,3,3]
    const float* fc1 = (const float*)d_in[3];   // [4096,16384]
    const float* fc2 = (const float*)d_in[4];   // [10,4096]
    float* out = (float*)d_out;                 // [32,10]

    float* ws = (float*)d_ws;
    // workspace layout (float slots)
    const size_t off_w2s   = 0;                          // 57344 (110592 bf16)
    const size_t off_spk1p = 57344;                      // 8388608 (16.8M bf16)
    const size_t off_spk2  = off_spk1p + 8388608;        // 2097152 (4.2M bf16)
    const size_t off_part  = off_spk2 + 2097152;         // 8388608
    const size_t off_spk3  = off_part + 8388608;         // 1048576
    __bf16* w2s   = (__bf16*)(ws + off_w2s);
    __bf16* spk1p = (__bf16*)(ws + off_spk1p);
    __bf16* spk2  = (__bf16*)(ws + off_spk2);
    float*  part  = ws + off_part;
    float*  spk3  = ws + off_spk3;

    k_conv1_if_pool<<<1024, 256, 0, stream>>>(x, w1, spk1p);
    k_w2s<<<144, 256, 0, stream>>>(w2, w2s);
    k_conv2_if_pool<<<256, 512, 0, stream>>>((const short*)spk1p,
                                             (const short*)w2s, spk2);
    k_fc1_mfma<<<512, 256, 0, stream>>>((const short*)spk2, fc1, part);
    k_fc1_if<<<512, 256, 0, stream>>>(part, spk3);
    k_fc2_if_mean<<<320, 256, 0, stream>>>(spk3, fc2, out);
}

// Round 17
// 588.323 us; speedup vs baseline: 1.0175x; 1.0004x over previous
//
#include <hip/hip_runtime.h>
#include <hip/hip_bf16.h>

// SNN forward: conv1(3->64,3x3,p1) -> IF -> pool2 -> conv2(64->64) -> IF -> pool2
//              -> fc1(16384->4096) -> IF -> fc2(4096->10) -> IF -> mean over T
// T=8 N=32 IMG=64.
// conv2 and fc1 use bf16 MFMA: spikes are exactly 0/1 (exact in bf16); fp32
// weights are 3-way bf16 split (hi+mid+lo; for fp32's 24-bit mantissa the
// three 8-bit bf16 chunks are usually an EXACT decomposition) -> three MFMAs
// into one fp32 accumulator == fp32 dot product to within fp32 rounding noise.
// conv1 (R14): packed v_pk_fma_f32 FMA loop; x tile DMA-staged LDS.
// fc1 (R14/R16): 256-thread blocks, 2 blocks/CU; wave = 128 M-rows x 32 outs;
// cooperative W split3 once per K-step -> pre-split bf16 LDS; A slab DMA
// double-buffer; counted-vmcnt barrier; setprio around MFMA cluster.
// conv2 (R17): k_w2s FUSED into the Bs staging — each block computes its
// ch-half's 3-way split directly into LDS (same split3 bits, same layout) ->
// one fewer kernel launch + no w2s global round-trip. A tile (zero-padded,
// 42.5 KB) DMA-staged per t; inner loop pure ds_read_b128 + MFMA.

#define T_STEPS 8
#define NB      32
#define CMID    64

typedef __bf16 bf16x2 __attribute__((ext_vector_type(2)));
typedef __bf16 bf16x4 __attribute__((ext_vector_type(4)));
typedef __bf16 bf16x8 __attribute__((ext_vector_type(8)));
typedef short  s16x4  __attribute__((ext_vector_type(4)));
typedef short  s16x8  __attribute__((ext_vector_type(8)));
typedef float  f32x2  __attribute__((ext_vector_type(2)));
typedef float  f32x4  __attribute__((ext_vector_type(4)));

struct Split3 { float h, m, l; };
__device__ __forceinline__ Split3 split3(float x) {
    Split3 s;
    __bf16 h = (__bf16)x;
    float r1 = x - (float)h;
    __bf16 m = (__bf16)r1;
    float r2 = r1 - (float)m;
    __bf16 l = (__bf16)r2;
    s.h = (float)h; s.m = (float)m; s.l = (float)l;
    return s;
}

// split 4 fp32 into three bf16x4 (hi/mid/lo), bit-identical to split3()
__device__ __forceinline__ void split3w4(float4 v, s16x4& fh, s16x4& fm,
                                         s16x4& fl) {
    float x[4] = {v.x, v.y, v.z, v.w};
    s16x4 h, m, l;
#pragma unroll
    for (int j = 0; j < 4; j++) {
        __bf16 ch = (__bf16)x[j];
        float r1 = x[j] - (float)ch;
        __bf16 cm = (__bf16)r1;
        float r2 = r1 - (float)cm;
        __bf16 cl = (__bf16)r2;
        h[j] = __builtin_bit_cast(short, ch);
        m[j] = __builtin_bit_cast(short, cm);
        l[j] = __builtin_bit_cast(short, cl);
    }
    fh = h; fm = m; fl = l;
}

// async global(16B/lane) -> LDS, wave-uniform dest base + lane*16
__device__ __forceinline__ void load_lds16(const void* g, void* l) {
    __builtin_amdgcn_global_load_lds(
        (const __attribute__((address_space(1))) void*)g,
        (__attribute__((address_space(3))) void*)l, 16, 0, 0);
}

// ------------------------------------------ conv1 + IF + maxpool -> NHWC bf16
// x tile DMA-staged in LDS, double-buffered across t; FMA loop packed as
// v_pk_fma_f32 pairs (a0,a1)/(a2,a3). Values bit-identical to the scalar
// bounds-checked original.
__global__ __launch_bounds__(256) void k_conv1_if_pool(
        const float* __restrict__ x, const float* __restrict__ w1,
        __bf16* __restrict__ spk1p) {
    int b    = blockIdx.x;              // 1024 = 32n * 8cog * 4pht
    int n    = b >> 5;
    int cog  = (b >> 2) & 7;
    int pht  = b & 3;
    int tid  = threadIdx.x;
    int pw   = tid & 31;
    int phl  = tid >> 5;                // 0..7 (local pooled row)
    int wv   = tid >> 6;                // 0..3
    int lane = tid & 63;

    // tile row tr <-> global row gr = 16*pht - 1 + tr, tr in [0,17]
    __shared__ float Xt[2][3][18][64];  // 27.6 KB

    {   // zero both buffers once (covers never-DMA'd OOB rows for pht 0/3)
        float* xz = &Xt[0][0][0][0];
        for (int i = tid; i < 6912; i += 256) xz[i] = 0.f;
    }

    int trlo = (pht == 0) ? 1 : 0;      // valid tile rows [trlo, trhi]
    int trhi = (pht == 3) ? 16 : 17;

    // stage x[t] tile into Xt[buf]: 15 wave-uniform 4-row (1 KB) issues,
    // last issue per ci overlaps to cover the 17/18-row range exactly.
    auto stage = [&](int t, int buf) {
        const float* xb = x + (size_t)(t * NB + n) * 3 * 4096;
        for (int i = wv; i < 15; i += 4) {
            int ci  = i / 5, q = i % 5;
            int tr0 = (q < 4) ? (trlo + 4 * q) : (trhi - 3);
            int gr0 = 16 * pht - 1 + tr0;
            const float* src = xb + ci * 4096 + (gr0 + (lane >> 4)) * 64
                             + (lane & 15) * 4;
            load_lds16(src, &Xt[buf][ci][tr0][0]);
        }
    };

    __syncthreads();
    stage(0, 0);
    __syncthreads();

    bool pw0  = (pw == 0);
    bool pw31 = (pw == 31);
    int  cl   = pw0 ? 0 : (2 * pw - 1);   // clamped halo cols
    int  cr   = pw31 ? 63 : (2 * pw + 2);

    float v[8][4];
#pragma unroll
    for (int a = 0; a < 8; a++)
#pragma unroll
        for (int p = 0; p < 4; p++) v[a][p] = 0.f;

    for (int t = 0; t < T_STEPS; t++) {
        int buf = t & 1;
        if (t < T_STEPS - 1) stage(t + 1, buf ^ 1);

        float patch[3][4][4];
#pragma unroll
        for (int ci = 0; ci < 3; ci++)
#pragma unroll
            for (int dy = 0; dy < 4; dy++) {
                int tr = 2 * phl + dy;                  // 0..17
                const float* row = &Xt[buf][ci][tr][0];
                float2 mid = *(const float2*)(row + 2 * pw);
                float lv = row[cl];
                float rv = row[cr];
                patch[ci][dy][0] = pw0 ? 0.f : lv;
                patch[ci][dy][1] = mid.x;
                patch[ci][dy][2] = mid.y;
                patch[ci][dy][3] = pw31 ? 0.f : rv;
            }
        bf16x8 sv;
#pragma unroll
        for (int c8 = 0; c8 < 8; c8++) {
            int co = cog * 8 + c8;
            const float* wc = w1 + co * 27;   // wave-uniform -> s_load
            f32x2 a01 = {0.f, 0.f};           // (a0, a1): pool row ky
            f32x2 a23 = {0.f, 0.f};           // (a2, a3): pool row ky+1
#pragma unroll
            for (int ci = 0; ci < 3; ci++)
#pragma unroll
                for (int ky = 0; ky < 3; ky++)
#pragma unroll
                    for (int kx = 0; kx < 3; kx++) {
                        float w = wc[ci * 9 + ky * 3 + kx];
                        f32x2 wv2 = {w, w};
                        f32x2 p01 = {patch[ci][ky][kx],
                                     patch[ci][ky][kx + 1]};
                        f32x2 p23 = {patch[ci][ky + 1][kx],
                                     patch[ci][ky + 1][kx + 1]};
                        a01 = __builtin_elementwise_fma(wv2, p01, a01);
                        a23 = __builtin_elementwise_fma(wv2, p23, a23);
                    }
            float s0, s1, s2, s3;
            v[c8][0] += a01[0]; s0 = (v[c8][0] >= 1.f) ? 1.f : 0.f; if (s0 > 0.f) v[c8][0] = 0.f;
            v[c8][1] += a01[1]; s1 = (v[c8][1] >= 1.f) ? 1.f : 0.f; if (s1 > 0.f) v[c8][1] = 0.f;
            v[c8][2] += a23[0]; s2 = (v[c8][2] >= 1.f) ? 1.f : 0.f; if (s2 > 0.f) v[c8][2] = 0.f;
            v[c8][3] += a23[1]; s3 = (v[c8][3] >= 1.f) ? 1.f : 0.f; if (s3 > 0.f) v[c8][3] = 0.f;
            sv[c8] = (__bf16)fmaxf(fmaxf(s0, s1), fmaxf(s2, s3));
        }
        *(bf16x8*)(spk1p + ((size_t)(t * NB + n) * 1024
                            + (pht * 8 + phl) * 32 + pw) * 64 + cog * 8) = sv;

        __syncthreads();   // drains DMA (t+1 tile ready) + guards buf reuse
    }
}

// -------------------------------- conv2 (MFMA) + IF + maxpool fused, t in-kernel
// Bs staging now computes the 3-way split of w2 directly (k_w2s fused):
// per thread 36 weights: e = i*512+tid decomposes to (tap,kh,oh,lane,j);
// co = ch*32+oh*16+(lane&15), ci = kh*32+(lane>>4)*8+j;
// within-half offset = (((tap*2+kh)*2+oh)*3)*512 + lane*8 + j, sp at +512.
// Identical split3 bits + layout as the old k_w2s -> bit-identical.
__global__ __launch_bounds__(512, 2) void k_conv2_if_pool(
        const short* __restrict__ spk1p,   // [256][32][32][64] bf16 bits
        const float* __restrict__ w2,      // [64][64][3][3] fp32
        __bf16* __restrict__ spk2) {       // [256][64][16][16]
    int b     = blockIdx.x;                // 256 = 32n * 4s2 * 2ch
    int ch    = b & 1;
    int s2    = (b >> 1) & 3;
    int n     = b >> 3;
    int tid   = threadIdx.x;
    int lane  = tid & 63;
    int wv    = tid >> 6;                  // 0..7
    int mh    = wv >> 1, oh = wv & 1;      // mh 0..3
    int lm    = lane & 15, kq = lane >> 4;

    __shared__ short Bs[55296];            // 108 KB: 9tap x 2kh x 2oh x 3sp x 512
    __shared__ short As[10 * 34 * 64];     // 42.5 KB

    {
        // fused w2 split -> Bs (replaces k_w2s + global round-trip)
#pragma unroll 4
        for (int i = 0; i < 36; i++) {
            int e    = i * 512 + tid;      // 0..18431
            int j    = e & 7;
            int ln   = (e >> 3) & 63;
            int ohh  = (e >> 9) & 1;
            int khh  = (e >> 10) & 1;
            int tap  = e >> 11;            // 0..8
            int co_  = ch * 32 + ohh * 16 + (ln & 15);
            int ci_  = khh * 32 + (ln >> 4) * 8 + j;
            float w  = w2[co_ * 576 + ci_ * 9 + tap];
            Split3 s = split3(w);
            __bf16* o = (__bf16*)Bs + (((tap * 2 + khh) * 2 + ohh) * 3) * 512
                      + ln * 8 + j;
            o[0]    = (__bf16)s.h;
            o[512]  = (__bf16)s.m;
            o[1024] = (__bf16)s.l;
        }
        // zero whole A tile once: pad cols (widx 0,33) + out-of-image rows
        // stay zero forever (DMA never writes them).
        uint4* za = (uint4*)As;
        for (int i = tid; i < 2720; i += 512) za[i] = (uint4){0, 0, 0, 0};
    }
    __syncthreads();
    const short* Bsw = Bs + oh * 1536;

    int wl  = lane >> 3;
    int sph = lane & 7;

    f32x4 v[4];
#pragma unroll
    for (int i = 0; i < 4; i++) v[i] = (f32x4){0.f, 0.f, 0.f, 0.f};

    int co = ch * 32 + oh * 16 + lm;
    int pH = s2 * 4 + mh;

#pragma unroll 1
    for (int t = 0; t < T_STEPS; t++) {
        const short* img = spk1p + (size_t)(t * NB + n) * 65536;

        if (t > 0) __syncthreads();
#pragma unroll
        for (int q = 0; q < 5; q++) {
            int u = q * 8 + wv;            // 0..39, wave-uniform
            int r = u >> 2;
            int quarter = u & 3;
            int hh = s2 * 8 - 1 + r;
            if ((unsigned)hh < 32u) {
                int widx = quarter * 8 + 1 + wl;
                int slog = sph ^ (widx & 7);
                const short* src = img + (size_t)(hh * 32 + widx - 1) * 64
                                       + slog * 8;
                short* dst = As + (r * 34 + quarter * 8 + 1) * 64;
                load_lds16(src, dst);
            }
        }
        __syncthreads();                   // drains DMA: As[t] ready

        f32x4 acc[4];
#pragma unroll
        for (int i = 0; i < 4; i++) acc[i] = (f32x4){0.f, 0.f, 0.f, 0.f};

#pragma unroll 1
        for (int dy = 0; dy < 3; dy++) {
#pragma unroll 1
            for (int dx = 0; dx < 3; dx++) {
                const short* bp = Bsw + (dy * 3 + dx) * 6144 + lane * 8;
                s16x8 bf[2][3];
#pragma unroll
                for (int kh = 0; kh < 2; kh++)
#pragma unroll
                    for (int sp = 0; sp < 3; sp++)
                        bf[kh][sp] = *(const s16x8*)(bp + kh * 3072 + sp * 512);
#pragma unroll
                for (int i = 0; i < 4; i++) {
                    int r    = 2 * mh + (i >> 1) + dy;              // 0..9
                    int widx = (i & 1) * 16 + lm + dx;              // 0..33
                    const short* ap = As + (r * 34 + widx) * 64;
                    s16x8 a0 = *(const s16x8*)(ap + ((kq    ) ^ (widx & 7)) * 8);
                    s16x8 a1 = *(const s16x8*)(ap + ((kq + 4) ^ (widx & 7)) * 8);
#pragma unroll
                    for (int sp = 0; sp < 3; sp++) {
                        acc[i] = __builtin_amdgcn_mfma_f32_16x16x32_bf16(
                            a0, bf[0][sp], acc[i], 0, 0, 0);
                        acc[i] = __builtin_amdgcn_mfma_f32_16x16x32_bf16(
                            a1, bf[1][sp], acc[i], 0, 0, 0);
                    }
                }
            }
        }
        float s[4][4];
#pragma unroll
        for (int i = 0; i < 4; i++)
#pragma unroll
            for (int r = 0; r < 4; r++) {
                float vv = v[i][r] + acc[i][r];
                float sp = (vv >= 1.f) ? 1.f : 0.f;
                s[i][r] = sp;
                v[i][r] = (sp > 0.f) ? 0.f : vv;
            }
        __bf16* op = spk2 + ((size_t)(t * NB + n) * 64 + co) * 256 + pH * 16
                   + kq * 2;
#pragma unroll
        for (int i2 = 0; i2 < 2; i2++) {
            float p0 = fmaxf(fmaxf(s[i2][0], s[i2][1]),
                             fmaxf(s[i2 + 2][0], s[i2 + 2][1]));
            float p1 = fmaxf(fmaxf(s[i2][2], s[i2][3]),
                             fmaxf(s[i2 + 2][2], s[i2 + 2][3]));
            bf16x2 pv = {(__bf16)p0, (__bf16)p1};
            *(bf16x2*)(op + i2 * 8) = pv;
        }
    }
}

// ----------------------------------------------------------- fc1 via bf16 MFMA
// R14 config (best measured): 256-thread blocks (4 waves: mq 0..1 x oh 0..1),
// grid 512 = 2 blocks/CU. Wave owns 128 M-rows (av[8]) x 32 outputs.
// Cooperative W split3 once per K-step -> pre-split bf16 LDS; A slab DMA
// double-buffer; counted-vmcnt barrier; setprio around MFMA cluster.
__global__ __launch_bounds__(256, 2) void k_fc1_mfma(
        const short* __restrict__ A,      // spk2 bf16 bits [256][16384]
        const float* __restrict__ W,      // fc1 [4096][16384]
        float* __restrict__ part) {       // [8][256][4096]
    int b  = blockIdx.x;                  // 512 = 64nt * 8ks
    int nt = b & 63;
    int ks = b >> 6;
    int o0 = nt * 64;
    int kbase = ks * 2048;

    int tid  = threadIdx.x;
    int lane = tid & 63;
    int wv   = tid >> 6;                  // 0..3
    int mq   = wv >> 1;                   // M half (128 rows)
    int oh   = wv & 1;                    // output half (32 of 64)
    int lm   = lane & 15;
    int kq   = lane >> 4;

    __shared__ short Asm[2][8192];        // 2 x 16 KB A slab (swizzled)
    __shared__ short Wbf[2][6144];        // 2 x 12 KB pre-split W bf16

    const short* gA[4];
#pragma unroll
    for (int q = 0; q < 4; q++) {
        int p = q * 256 + tid;
        int r = p >> 2;
        int c = (p & 3) ^ ((r >> 1) & 3);
        gA[q] = A + (size_t)r * 16384 + kbase + c * 8;
    }

    int wrow = tid >> 2;                  // 0..63
    const float* gWf = W + (size_t)(o0 + wrow) * 16384 + kbase + (tid & 3) * 8;

    int wkc   = tid & 3;
    int wwoff = wrow * 32 + (wkc ^ ((wrow >> 1) & 3)) * 8;

    int aoff[8];
#pragma unroll
    for (int i = 0; i < 8; i++) {
        int r = mq * 128 + i * 16 + lm;
        aoff[i] = (r * 4 + (kq ^ ((r >> 1) & 3))) * 8;
    }
    int wroff[2];
#pragma unroll
    for (int oi = 0; oi < 2; oi++) {
        int row = (2 * oh + oi) * 16 + lm;
        wroff[oi] = row * 32 + (kq ^ ((row >> 1) & 3)) * 8;
    }

    f32x4 acc[8][2];
#pragma unroll
    for (int i = 0; i < 8; i++)
#pragma unroll
        for (int oi = 0; oi < 2; oi++) acc[i][oi] = (f32x4){0.f, 0.f, 0.f, 0.f};

    float4 wA0 = *(const float4*)gWf;         // W it=0
    float4 wA1 = *(const float4*)(gWf + 4);
#pragma unroll
    for (int q = 0; q < 4; q++)
        load_lds16(gA[q], &Asm[0][q * 2048 + wv * 512]);
    {
        s16x4 h4, m4, l4;
        split3w4(wA0, h4, m4, l4);
        *(s16x4*)&Wbf[0][wwoff]            = h4;
        *(s16x4*)&Wbf[0][2048 + wwoff]     = m4;
        *(s16x4*)&Wbf[0][4096 + wwoff]     = l4;
        split3w4(wA1, h4, m4, l4);
        *(s16x4*)&Wbf[0][wwoff + 4]        = h4;
        *(s16x4*)&Wbf[0][2048 + wwoff + 4] = m4;
        *(s16x4*)&Wbf[0][4096 + wwoff + 4] = l4;
    }
    float4 wB0 = *(const float4*)(gWf + 32);  // W it=1
    float4 wB1 = *(const float4*)(gWf + 36);
    asm volatile("s_waitcnt vmcnt(2) lgkmcnt(0)" ::: "memory");
    __builtin_amdgcn_s_barrier();
    __builtin_amdgcn_sched_barrier(0);

    auto body = [&](int it, float4& ws0, float4& ws1, float4& wl0,
                    float4& wl1) {
        int nb = (it + 1) & 1;
        if (it < 63) {
#pragma unroll
            for (int q = 0; q < 4; q++)
                load_lds16(gA[q] + (it + 1) * 32,
                           &Asm[nb][q * 2048 + wv * 512]);
            __builtin_amdgcn_sched_barrier(0);   // pin: DMAs before wload
            s16x4 h4, m4, l4;
            split3w4(ws0, h4, m4, l4);
            *(s16x4*)&Wbf[nb][wwoff]            = h4;
            *(s16x4*)&Wbf[nb][2048 + wwoff]     = m4;
            *(s16x4*)&Wbf[nb][4096 + wwoff]     = l4;
            split3w4(ws1, h4, m4, l4);
            *(s16x4*)&Wbf[nb][wwoff + 4]        = h4;
            *(s16x4*)&Wbf[nb][2048 + wwoff + 4] = m4;
            *(s16x4*)&Wbf[nb][4096 + wwoff + 4] = l4;
        }
        if (it < 62) {
            wl0 = *(const float4*)(gWf + (it + 2) * 32);
            wl1 = *(const float4*)(gWf + (it + 2) * 32 + 4);
            __builtin_amdgcn_sched_barrier(0);   // pin: wload issued here
        }

        const short* as = Asm[it & 1];
        const short* wb = Wbf[it & 1];
        s16x8 av[8];
#pragma unroll
        for (int i = 0; i < 8; i++)
            av[i] = *(const s16x8*)(as + aoff[i]);
        s16x8 bfr[3][2];
#pragma unroll
        for (int oi = 0; oi < 2; oi++)
#pragma unroll
            for (int sp = 0; sp < 3; sp++)
                bfr[sp][oi] = *(const s16x8*)(wb + sp * 2048 + wroff[oi]);

        __builtin_amdgcn_s_setprio(1);
#pragma unroll
        for (int i = 0; i < 8; i++)
#pragma unroll
            for (int oi = 0; oi < 2; oi++) {
                acc[i][oi] = __builtin_amdgcn_mfma_f32_16x16x32_bf16(
                    av[i], bfr[0][oi], acc[i][oi], 0, 0, 0);
                acc[i][oi] = __builtin_amdgcn_mfma_f32_16x16x32_bf16(
                    av[i], bfr[1][oi], acc[i][oi], 0, 0, 0);
                acc[i][oi] = __builtin_amdgcn_mfma_f32_16x16x32_bf16(
                    av[i], bfr[2][oi], acc[i][oi], 0, 0, 0);
            }
        __builtin_amdgcn_s_setprio(0);

        if (it < 62) {
            asm volatile("s_waitcnt vmcnt(2) lgkmcnt(0)" ::: "memory");
            __builtin_amdgcn_s_barrier();
            __builtin_amdgcn_sched_barrier(0);
        } else if (it == 62) {
            asm volatile("s_waitcnt vmcnt(0) lgkmcnt(0)" ::: "memory");
            __builtin_amdgcn_s_barrier();
            __builtin_amdgcn_sched_barrier(0);
        }
    };

#pragma unroll 1
    for (int j = 0; j < 32; ++j) {
        body(2 * j,     wB0, wB1, wA0, wA1);
        body(2 * j + 1, wA0, wA1, wB0, wB1);
    }

    int col = lane & 15;
    int rq  = (lane >> 4) * 4;
#pragma unroll
    for (int i = 0; i < 8; i++)
#pragma unroll
        for (int oi = 0; oi < 2; oi++)
#pragma unroll
            for (int r = 0; r < 4; r++) {
                int m = mq * 128 + i * 16 + rq + r;
                int o = o0 + (2 * oh + oi) * 16 + col;
                part[((size_t)ks * 256 + m) * 4096 + o] = acc[i][oi][r];
            }
}

// ----------------------------------------------- K-split reduce + IF for fc1
__global__ void k_fc1_if(const float* __restrict__ part,
                         float* __restrict__ spk3) {
    int idx = blockIdx.x * 256 + threadIdx.x;   // 131072
    int o = idx & 4095;
    int n = idx >> 12;
    float v = 0.f;
    for (int t = 0; t < T_STEPS; t++) {
        int m = t * NB + n;
        float s = 0.f;
#pragma unroll
        for (int ks = 0; ks < 8; ks++)
            s += part[((size_t)ks * 256 + m) * 4096 + o];
        v += s;
        float sp = (v >= 1.f) ? 1.f : 0.f;
        if (sp > 0.f) v = 0.f;
        spk3[(size_t)m * 4096 + o] = sp;
    }
}

// ------------------------------------------------------ fc2 + IF + time-mean
__global__ __launch_bounds__(256) void k_fc2_if_mean(
        const float* __restrict__ spk3, const float* __restrict__ fc2,
        float* __restrict__ out) {
    int b = blockIdx.x;                  // 320 = 32n * 10o
    int n = b / 10, o = b % 10;
    const float* wr = fc2 + o * 4096;
    __shared__ float red[256];
    int tid = threadIdx.x;
    float v = 0.f, cnt = 0.f;
    for (int t = 0; t < T_STEPS; t++) {
        const float* row = spk3 + (size_t)(t * NB + n) * 4096;
        float p = 0.f;
        for (int i = tid; i < 4096; i += 256) p += row[i] * wr[i];
        red[tid] = p;
        __syncthreads();
        for (int s = 128; s > 0; s >>= 1) {
            if (tid < s) red[tid] += red[tid + s];
            __syncthreads();
        }
        if (tid == 0) {
            v += red[0];
            float sp = (v >= 1.f) ? 1.f : 0.f;
            cnt += sp;
            if (sp > 0.f) v = 0.f;
        }
        __syncthreads();
    }
    if (tid == 0) out[n * 10 + o] = cnt * 0.125f;
}

// ---------------------------------------------------------------------- launch
extern "C" void kernel_launch(void* const* d_in, const int* in_sizes, int n_in,
                              void* d_out, int out_size, void* d_ws, size_t ws_size,
                              hipStream_t stream) {
    const float* x   = (const float*)d_in[0];   // [8,32,3,64,64]
    const float* w1  = (const float*)d_in[1];   // [64,3,3,3]
    const float* w2  = (const float*)d_in[2];   // [64,64,3,3]
    const float* fc1 = (const float*)d_in[3];   // [4096,16384]
    const float* fc2 = (const float*)d_in[4];   // [10,4096]
    float* out = (float*)d_out;                 // [32,10]

    float* ws = (float*)d_ws;
    // workspace layout (float slots)
    const size_t off_spk1p = 0;                          // 8388608 (16.8M bf16)
    const size_t off_spk2  = off_spk1p + 8388608;        // 2097152 (4.2M bf16)
    const size_t off_part  = off_spk2 + 2097152;         // 8388608
    const size_t off_spk3  = off_part + 8388608;         // 1048576
    __bf16* spk1p = (__bf16*)(ws + off_spk1p);
    __bf16* spk2  = (__bf16*)(ws + off_spk2);
    float*  part  = ws + off_part;
    float*  spk3  = ws + off_spk3;

    k_conv1_if_pool<<<1024, 256, 0, stream>>>(x, w1, spk1p);
    k_conv2_if_pool<<<256, 512, 0, stream>>>((const short*)spk1p, w2, spk2);
    k_fc1_mfma<<<512, 256, 0, stream>>>((const short*)spk2, fc1, part);
    k_fc1_if<<<512, 256, 0, stream>>>(part, spk3);
    k_fc2_if_mean<<<320, 256, 0, stream>>>(spk3, fc2, out);
}